// Round 17
// baseline (275.053 us; speedup 1.0000x reference)
//
#include <hip/hip_runtime.h>
#include <hip/hip_bf16.h>

#define B_   2
#define S_   2048
#define H_   16
#define HD_  128
#define D_   2048
#define BS_  4096
// 1/sqrt(128) * log2(e): q pre-scale puts QK^T scores in log2 domain (exp2 softmax)
#define QSCALE_ 0.12751742897f
#define DEFER_THR_ 11.541560327f   // 8 * log2(e)

typedef __hip_bfloat16 bf16;
typedef float f32x4 __attribute__((ext_vector_type(4)));
typedef __bf16 bf16x8 __attribute__((ext_vector_type(8)));
typedef unsigned short u16x8 __attribute__((ext_vector_type(8)));
typedef unsigned short u16x4 __attribute__((ext_vector_type(4)));

static __device__ __forceinline__ unsigned short f2bf_u(float f) {
  bf16 h = __float2bfloat16(f);
  return __builtin_bit_cast(unsigned short, h);
}
static __device__ __forceinline__ void load_lds16(const void* g, void* l) {
  __builtin_amdgcn_global_load_lds((const __attribute__((address_space(1))) void*)g,
                                   (__attribute__((address_space(3))) void*)l, 16, 0, 0);
}

// ---------------- fused prep: convert x | transpose weights | rope tables ----------------
__global__ __launch_bounds__(256) void k_prep(const float* __restrict__ x,
                                              bf16* __restrict__ xb,
                                              const float* __restrict__ in_proj,
                                              bf16* __restrict__ wqkvT,
                                              const float* __restrict__ out_proj,
                                              bf16* __restrict__ woT,
                                              float* __restrict__ cost,
                                              float* __restrict__ sint) {
  __shared__ float tile[64][65];
  const int bid = blockIdx.x;
  const int t = threadIdx.x;
  if (bid < 4096) {
    const size_t i = ((size_t)bid * 256 + t) * 8;
    const float4 a = *(const float4*)(x + i);
    const float4 b = *(const float4*)(x + i + 4);
    u16x8 o;
    o[0] = f2bf_u(a.x); o[1] = f2bf_u(a.y); o[2] = f2bf_u(a.z); o[3] = f2bf_u(a.w);
    o[4] = f2bf_u(b.x); o[5] = f2bf_u(b.y); o[6] = f2bf_u(b.z); o[7] = f2bf_u(b.w);
    *(u16x8*)(xb + i) = o;
  } else if (bid < 8192) {
    const int local = bid - 4096;
    const float* src;
    bf16* dst;
    if (local < 3072) {
      const int z = local >> 10;
      src = in_proj + (size_t)z * D_ * D_;
      dst = wqkvT + (size_t)z * D_ * D_;
    } else {
      src = out_proj;
      dst = woT;
    }
    const int rem = local & 1023;
    const int x0 = (rem & 31) * 64, y0 = (rem >> 5) * 64;
#pragma unroll
    for (int i = 0; i < 16; ++i) {
      int idx = t + i * 256, r = idx >> 6, c = idx & 63;
      tile[r][c] = src[(size_t)(y0 + r) * D_ + x0 + c];
    }
    __syncthreads();
#pragma unroll
    for (int i = 0; i < 16; ++i) {
      int idx = t + i * 256, c = idx >> 6, r = idx & 63;
      dst[(size_t)(x0 + c) * D_ + y0 + r] = __float2bfloat16(tile[r][c]);
    }
  } else {
    const int idx = (bid - 8192) * 256 + t;   // S_*64 total
    const int s = idx >> 6, d = idx & 63;
    const float inv = expf(-(float)d * (9.210340371976184f / 64.f)); // 10000^(-d/64)
    const float ang = (float)s * inv;
    cost[idx] = cosf(ang);
    sint[idx] = sinf(ang);
  }
}

// ============ 128xBN GEMM, BK=32 ============
// MODE 0: BN=256, 3-buf (72KB, 2 blocks/CU), counted vmcnt(3) — round-13 proven (121 us;
//         round-16 showed 2-buf full-residency is WORSE here: depth > occupancy at BN=256).
// MODE 1: BN=128, 2-buf (32KB): 4 blocks/CU, grid 512 fully resident (round-15 proven).
// NO XCD swizzle (round-14: natural dispatch keeps A-panels L2-local; remap regressed).
template <int MODE>
__global__ __launch_bounds__(512, 4) void k_gemm_p(const bf16* __restrict__ A,
                                                   const bf16* __restrict__ Bt,
                                                   float* __restrict__ Cf,
                                                   bf16* __restrict__ qb,
                                                   bf16* __restrict__ kb,
                                                   bf16* __restrict__ vt,
                                                   const float* __restrict__ cost,
                                                   const float* __restrict__ sint) {
  constexpr int BN = (MODE == 1) ? 128 : 256;
  constexpr int NF = BN / 64;                    // col fragments per wave
  constexpr int NBUF = (MODE == 1) ? 2 : 3;
  constexpr int BSTRIDE = 8192 + BN * 64;        // bytes per LDS buffer
  extern __shared__ __align__(16) char smem[];
  const int tid = threadIdx.x;
  const int w = tid >> 6, lane = tid & 63;
  const int wm = w >> 2, wn = w & 3;
  const int lr = lane & 15, lg = lane >> 4;
  const int brow = blockIdx.x * 128, bcol = blockIdx.y * BN;

  f32x4 acc[4][NF] = {};

  auto stage = [&](int kt, int buf) {
    char* base = smem + buf * BSTRIDE;
    {  // A tile 128x32 (8KB): 1 load/thread
      const int row = tid >> 2, su = tid & 3;
      const int up = su ^ ((row >> 1) & 3);
      load_lds16(A + (size_t)(brow + row) * D_ + kt * 32 + up * 8, base + w * 1024);
    }
#pragma unroll
    for (int i = 0; i < BN / 128; ++i) {  // B tile BNx32: BN/128 loads/thread
      const int slot = i * 512 + tid;
      const int row = slot >> 2, su = slot & 3;
      const int up = su ^ ((row >> 1) & 3);
      load_lds16(Bt + (size_t)(bcol + row) * D_ + kt * 32 + up * 8,
                 base + 8192 + i * 8192 + w * 1024);
    }
  };

  const int NKT = D_ / 32;                       // 64
  if (MODE == 1) {
    stage(0, 0);
  } else {
    stage(0, 0); stage(1, 1);
  }
  int bs = 0;                                    // kt % NBUF
  for (int kt = 0; kt < NKT; ++kt) {
    if (MODE == 1) {
      asm volatile("s_waitcnt vmcnt(0)" ::: "memory");
    } else {
      if (kt < NKT - 1) asm volatile("s_waitcnt vmcnt(3)" ::: "memory");
      else              asm volatile("s_waitcnt vmcnt(0)" ::: "memory");
    }
    __builtin_amdgcn_s_barrier();                // raw: prefetch loads stay in flight
    __builtin_amdgcn_sched_barrier(0);
    if (MODE == 1) {
      if (kt + 1 < NKT) stage(kt + 1, (kt + 1) & 1);
    } else {
      if (kt + 2 < NKT) {
        int sb = bs + 2; if (sb >= 3) sb -= 3;
        stage(kt + 2, sb);
      }
    }

    const char* base = smem + bs * BSTRIDE;
    bf16x8 af[4], bf4[NF];
#pragma unroll
    for (int q = 0; q < 4; ++q) {
      const int r = wm * 64 + q * 16 + lr;
      af[q] = *(const bf16x8*)(base + r * 64 + ((lg ^ ((r >> 1) & 3)) * 16));
    }
#pragma unroll
    for (int nf = 0; nf < NF; ++nf) {
      const int r = wn * (NF * 16) + nf * 16 + lr;
      bf4[nf] = *(const bf16x8*)(base + 8192 + r * 64 + ((lg ^ ((r >> 1) & 3)) * 16));
    }
    __builtin_amdgcn_s_setprio(1);
#pragma unroll
    for (int q = 0; q < 4; ++q)
#pragma unroll
      for (int nf = 0; nf < NF; ++nf)
        acc[q][nf] = __builtin_amdgcn_mfma_f32_16x16x32_bf16(af[q], bf4[nf], acc[q][nf], 0, 0, 0);
    __builtin_amdgcn_s_setprio(0);
    bs = (bs == NBUF - 1) ? 0 : bs + 1;
  }

  if (MODE == 1) {
#pragma unroll
    for (int mf = 0; mf < 4; ++mf)
#pragma unroll
      for (int nf = 0; nf < NF; ++nf) {
        const int col = bcol + wn * (NF * 16) + nf * 16 + lr;
#pragma unroll
        for (int j = 0; j < 4; ++j) {
          const int row = brow + wm * 64 + mf * 16 + lg * 4 + j;
          Cf[(size_t)row * D_ + col] = acc[mf][nf][j];
        }
      }
  } else {
    const int t = bcol >> 11;                     // block-uniform (256 | 2048)
#pragma unroll
    for (int mf = 0; mf < 4; ++mf)
#pragma unroll
      for (int nf = 0; nf < NF; ++nf) {
        const int col = bcol + wn * (NF * 16) + nf * 16 + lr;
        const int h = (col >> 7) & (H_ - 1), mm = col & (HD_ - 1);
        if (t == 2) {
          const int row0 = brow + wm * 64 + mf * 16 + lg * 4;
          const int b = row0 >> 11, s0 = row0 & (S_ - 1);
          u16x4 pk;
#pragma unroll
          for (int j = 0; j < 4; ++j) pk[j] = f2bf_u(acc[mf][nf][j]);
          *(u16x4*)(vt + ((size_t)(b * H_ + h) * HD_ + mm) * S_ + s0) = pk;
        } else {
          const int i2 = mm >> 1;
          const bool odd = mm & 1;
#pragma unroll
          for (int j = 0; j < 4; ++j) {
            const int row = brow + wm * 64 + mf * 16 + lg * 4 + j;
            const int b = row >> 11, s = row & (S_ - 1);
            const float val = acc[mf][nf][j];
            const float part = __shfl_xor(val, 1, 64);   // col parity == lane parity
            const float c = cost[s * 64 + i2];
            const float sn = sint[s * 64 + i2];
            float o = odd ? (part * sn + val * c) : (val * c - part * sn);
            if (t == 0) o *= QSCALE_;                    // 1/sqrt(d) * log2(e)
            const int om = odd ? (64 + i2) : i2;
            bf16* dst = (t == 1) ? kb : qb;
            dst[((size_t)(b * H_ + h) * S_ + s) * HD_ + om] = __float2bfloat16(o);
          }
        }
      }
  }
}

// ---------------- flash attention: 512 threads, 8 waves x ONE 16-row group ----------------
// exp2-domain softmax: q pre-scaled by 1/sqrt(d)*log2e, so p = exp2(s - m) directly
// (v_exp_f32 is base-2; removes the per-exp *log2e mul from the serial chain).
// l_run is a per-lane partial (cross-lane reduce deferred to epilogue, round-16 win).
__global__ __launch_bounds__(512, 4) void k_attn(const bf16* __restrict__ qb,
                                                 const bf16* __restrict__ kb,
                                                 const bf16* __restrict__ vt,
                                                 const int* __restrict__ mask,
                                                 bf16* __restrict__ attn_b) {
  const int tid = threadIdx.x, w = tid >> 6, lane = tid & 63;
  const int lr = lane & 15, lg = lane >> 4;
  const int qt = (blockIdx.y < 16) ? ((int)gridDim.x - 1 - (int)blockIdx.x)
                                   : (int)blockIdx.x;   // complementary CU pairing
  const int q0 = qt * 128;
  const int bh = blockIdx.y;
  const int b = bh >> 4, h = bh & (H_ - 1);
  const bf16* qp = qb + (size_t)bh * S_ * HD_;
  const bf16* kp = kb + (size_t)bh * S_ * HD_;
  const bf16* vp = vt + (size_t)bh * HD_ * S_;
  __shared__ __align__(16) bf16 Ks[2][64 * 128];   // 2 x 16 KB, XOR-swizzled rows
  __shared__ __align__(16) bf16 Vs[2][128 * 64];   // 2 x 16 KB, XOR-swizzled rows
  __shared__ __align__(16) bf16 Ps[8][16][40];     // per-wave half-P scratch

  const int qrow = q0 + w * 16 + lr;
  bf16x8 qf[4];
#pragma unroll
  for (int ks = 0; ks < 4; ++ks)
    qf[ks] = *(const bf16x8*)(qp + (size_t)qrow * HD_ + ks * 32 + lg * 8);

  float m_run[4], l_run[4];
  f32x4 oacc[8];
#pragma unroll
  for (int j = 0; j < 4; ++j) { m_run[j] = -INFINITY; l_run[j] = 0.f; }
#pragma unroll
  for (int c = 0; c < 8; ++c) oacc[c] = (f32x4)(0.f);

  auto stage = [&](int buf, int k0) {
#pragma unroll
    for (int i = 0; i < 2; ++i) {
      const int slot = i * 512 + tid;
      const int row = slot >> 4, j16 = slot & 15;
      load_lds16(kp + (size_t)(k0 + row) * HD_ + ((j16 ^ (row & 7)) * 8),
                 (char*)&Ks[buf][0] + i * 8192 + w * 1024);
    }
#pragma unroll
    for (int i = 0; i < 2; ++i) {
      const int slot = i * 512 + tid;
      const int row = slot >> 3, j8 = slot & 7;
      load_lds16(vp + (size_t)row * S_ + k0 + ((j8 ^ (row & 7)) * 8),
                 (char*)&Vs[buf][0] + i * 8192 + w * 1024);
    }
  };

  const int nt = 2 * qt + 2;
  stage(0, 0);
  asm volatile("s_waitcnt vmcnt(0)" ::: "memory");
  __builtin_amdgcn_s_barrier();
  __builtin_amdgcn_sched_barrier(0);

  int cur = 0;
  for (int it = 0; it < nt; ++it) {
    const int k0 = it * 64;
    if (it + 1 < nt) stage(cur ^ 1, k0 + 64);   // prefetch next tile (in flight across compute)

    // waves 0-3: rows q0+w*16..+15 all < q0+64 <= k0 on the last tile -> fully masked, skip
    const bool active = (it + 1 < nt) || (w >= 4);

    if (active) {
      int mk4[4];
#pragma unroll
      for (int n = 0; n < 4; ++n) mk4[n] = mask[b * S_ + k0 + n * 16 + lr];

      const bf16* ksb = &Ks[cur][0];
      const bf16* vsb = &Vs[cur][0];

      // QK^T: 16 q-rows x 64 k (scores already in log2 domain via q pre-scale)
      f32x4 sacc[4] = {};
      __builtin_amdgcn_s_setprio(1);
#pragma unroll
      for (int n = 0; n < 4; ++n) {
        const int krow = n * 16 + lr;
#pragma unroll
        for (int ks = 0; ks < 4; ++ks) {
          const int j16 = (ks * 4 + lg) ^ (krow & 7);
          const bf16x8 kf = *(const bf16x8*)(ksb + krow * 128 + j16 * 8);
          sacc[n] = __builtin_amdgcn_mfma_f32_16x16x32_bf16(qf[ks], kf, sacc[n], 0, 0, 0);
        }
      }
      __builtin_amdgcn_s_setprio(0);

      // mask + row max
      float mblk[4] = {-INFINITY, -INFINITY, -INFINITY, -INFINITY};
#pragma unroll
      for (int n = 0; n < 4; ++n) {
        const int kcol = k0 + n * 16 + lr;
#pragma unroll
        for (int j = 0; j < 4; ++j) {
          const int r = q0 + w * 16 + lg * 4 + j;
          float sv = sacc[n][j];
          const bool allowed = (kcol <= r) && (mk4[n] != 0 || kcol == r);
          sv = allowed ? sv : -1e9f;
          sacc[n][j] = sv;
          mblk[j] = fmaxf(mblk[j], sv);
        }
      }
#pragma unroll
      for (int xm = 1; xm < 16; xm <<= 1)
#pragma unroll
        for (int j = 0; j < 4; ++j)
          mblk[j] = fmaxf(mblk[j], __shfl_xor(mblk[j], xm, 64));

      // defer-max (T13), threshold in log2 units; l_run per-lane partial
      bool grow = false;
#pragma unroll
      for (int j = 0; j < 4; ++j) grow = grow || (mblk[j] > m_run[j] + DEFER_THR_);
      if (__any(grow)) {
        float alpha[4];
#pragma unroll
        for (int j = 0; j < 4; ++j) {
          const float mn = fmaxf(m_run[j], mblk[j]);
          alpha[j] = exp2f(m_run[j] - mn);
          m_run[j] = mn;
          l_run[j] *= alpha[j];
        }
#pragma unroll
        for (int c = 0; c < 8; ++c)
#pragma unroll
          for (int j = 0; j < 4; ++j) oacc[c][j] *= alpha[j];
      }

      // p = exp2(s - m); accumulate per-lane l partials
#pragma unroll
      for (int n = 0; n < 4; ++n)
#pragma unroll
        for (int j = 0; j < 4; ++j) {
          const float p = exp2f(sacc[n][j] - m_run[j]);
          l_run[j] += p;
          sacc[n][j] = p;
        }

      // PV in two 32-col halves through the per-wave half-P scratch (in-order reuse)
#pragma unroll
      for (int hh = 0; hh < 2; ++hh) {
#pragma unroll
        for (int n2 = 0; n2 < 2; ++n2)
#pragma unroll
          for (int j = 0; j < 4; ++j)
            Ps[w][lg * 4 + j][n2 * 16 + lr] = __float2bfloat16(sacc[hh * 2 + n2][j]);
        const bf16x8 pa = *(const bf16x8*)(&Ps[w][lr][lg * 8]);
        __builtin_amdgcn_s_setprio(1);
#pragma unroll
        for (int c = 0; c < 8; ++c) {
          const int vrow = c * 16 + lr;
          const int unit = (hh * 4 + lg) ^ (vrow & 7);
          const bf16x8 vf = *(const bf16x8*)(vsb + vrow * 64 + unit * 8);
          oacc[c] = __builtin_amdgcn_mfma_f32_16x16x32_bf16(pa, vf, oacc[c], 0, 0, 0);
        }
        __builtin_amdgcn_s_setprio(0);
      }
    }

    asm volatile("s_waitcnt vmcnt(0)" ::: "memory");  // next tile staged (all waves)
    __builtin_amdgcn_s_barrier();                      // raw: no redundant re-drain
    __builtin_amdgcn_sched_barrier(0);
    cur ^= 1;
  }

  // epilogue: single cross-lane l reduce, then normalize and write attn_b [B,S,H*hd] bf16
#pragma unroll
  for (int xm = 1; xm < 16; xm <<= 1)
#pragma unroll
    for (int j = 0; j < 4; ++j)
      l_run[j] += __shfl_xor(l_run[j], xm, 64);
#pragma unroll
  for (int j = 0; j < 4; ++j) {
    const float inv = 1.f / l_run[j];
    const int r = q0 + w * 16 + lg * 4 + j;
#pragma unroll
    for (int c = 0; c < 8; ++c)
      attn_b[(size_t)(b * S_ + r) * D_ + h * HD_ + c * 16 + lr] =
          __float2bfloat16(oacc[c][j] * inv);
  }
}

extern "C" void kernel_launch(void* const* d_in, const int* in_sizes, int n_in,
                              void* d_out, int out_size, void* d_ws, size_t ws_size,
                              hipStream_t stream) {
  (void)in_sizes; (void)n_in; (void)out_size; (void)ws_size;
  const float* x        = (const float*)d_in[0];
  const int*   attn_mask= (const int*)d_in[1];
  const float* in_proj  = (const float*)d_in[2];
  const float* out_proj = (const float*)d_in[3];
  float* out = (float*)d_out;
  char* ws = (char*)d_ws;

  bf16*  xb    = (bf16*)(ws + 0);            // 16 MB (also attn_b later)
  bf16*  wqkvT = (bf16*)(ws + 16777216);     // 24 MB  ([3][2048][2048] = [6144][2048])
  bf16*  woT   = (bf16*)(ws + 41943040);     //  8 MB
  float* cost  = (float*)(ws + 50331648);
  float* sint  = (float*)(ws + 50855936);
  bf16*  vt    = (bf16*)(ws + 51380224);     // 16 MB
  bf16* qb = (bf16*)d_out;                   // d_out as scratch (dead before final GEMM)
  bf16* kb = (bf16*)((char*)d_out + 16777216);
  bf16* attn_b = xb;

  // allow dynamic LDS (host-side, graph-capture safe)
  static int lds_ok = 0;
  if (!lds_ok) {
    (void)hipFuncSetAttribute((const void*)k_gemm_p<0>,
                              hipFuncAttributeMaxDynamicSharedMemorySize, 73728);
    (void)hipFuncSetAttribute((const void*)k_gemm_p<1>,
                              hipFuncAttributeMaxDynamicSharedMemorySize, 32768);
    lds_ok = 1;
  }

  k_prep<<<8704, 256, 0, stream>>>(x, xb, in_proj, wqkvT, out_proj, woT, cost, sint);
  k_gemm_p<0><<<dim3(32, 24), 512, 73728, stream>>>(xb, wqkvT, nullptr, qb, kb, vt, cost, sint);
  k_attn<<<dim3(16, 32), 512, 0, stream>>>(qb, kb, vt, attn_mask, attn_b);
  k_gemm_p<1><<<dim3(32, 16), 512, 32768, stream>>>(attn_b, woT, out, nullptr, nullptr, nullptr,
                                                    nullptr, nullptr);
}

// Round 18
// 269.370 us; speedup vs baseline: 1.0211x; 1.0211x over previous
//
#include <hip/hip_runtime.h>
#include <hip/hip_bf16.h>

#define B_   2
#define S_   2048
#define H_   16
#define HD_  128
#define D_   2048
#define BS_  4096
#define SCALE_ 0.08838834764831845f   // 1/sqrt(128), applied in QKV epilogue (t==0)

typedef __hip_bfloat16 bf16;
typedef float f32x4 __attribute__((ext_vector_type(4)));
typedef __bf16 bf16x8 __attribute__((ext_vector_type(8)));
typedef unsigned short u16x8 __attribute__((ext_vector_type(8)));
typedef unsigned short u16x4 __attribute__((ext_vector_type(4)));

static __device__ __forceinline__ unsigned short f2bf_u(float f) {
  bf16 h = __float2bfloat16(f);
  return __builtin_bit_cast(unsigned short, h);
}
static __device__ __forceinline__ void load_lds16(const void* g, void* l) {
  __builtin_amdgcn_global_load_lds((const __attribute__((address_space(1))) void*)g,
                                   (__attribute__((address_space(3))) void*)l, 16, 0, 0);
}

// ---------------- fused prep: convert x | transpose weights | rope tables ----------------
__global__ __launch_bounds__(256) void k_prep(const float* __restrict__ x,
                                              bf16* __restrict__ xb,
                                              const float* __restrict__ in_proj,
                                              bf16* __restrict__ wqkvT,
                                              const float* __restrict__ out_proj,
                                              bf16* __restrict__ woT,
                                              float* __restrict__ cost,
                                              float* __restrict__ sint) {
  __shared__ float tile[64][65];
  const int bid = blockIdx.x;
  const int t = threadIdx.x;
  if (bid < 4096) {
    const size_t i = ((size_t)bid * 256 + t) * 8;
    const float4 a = *(const float4*)(x + i);
    const float4 b = *(const float4*)(x + i + 4);
    u16x8 o;
    o[0] = f2bf_u(a.x); o[1] = f2bf_u(a.y); o[2] = f2bf_u(a.z); o[3] = f2bf_u(a.w);
    o[4] = f2bf_u(b.x); o[5] = f2bf_u(b.y); o[6] = f2bf_u(b.z); o[7] = f2bf_u(b.w);
    *(u16x8*)(xb + i) = o;
  } else if (bid < 8192) {
    const int local = bid - 4096;
    const float* src;
    bf16* dst;
    if (local < 3072) {
      const int z = local >> 10;
      src = in_proj + (size_t)z * D_ * D_;
      dst = wqkvT + (size_t)z * D_ * D_;
    } else {
      src = out_proj;
      dst = woT;
    }
    const int rem = local & 1023;
    const int x0 = (rem & 31) * 64, y0 = (rem >> 5) * 64;
#pragma unroll
    for (int i = 0; i < 16; ++i) {
      int idx = t + i * 256, r = idx >> 6, c = idx & 63;
      tile[r][c] = src[(size_t)(y0 + r) * D_ + x0 + c];
    }
    __syncthreads();
#pragma unroll
    for (int i = 0; i < 16; ++i) {
      int idx = t + i * 256, c = idx >> 6, r = idx & 63;
      dst[(size_t)(x0 + c) * D_ + y0 + r] = __float2bfloat16(tile[r][c]);
    }
  } else {
    const int idx = (bid - 8192) * 256 + t;   // S_*64 total
    const int s = idx >> 6, d = idx & 63;
    const float inv = expf(-(float)d * (9.210340371976184f / 64.f)); // 10000^(-d/64)
    const float ang = (float)s * inv;
    cost[idx] = cosf(ang);
    sint[idx] = sinf(ang);
  }
}

// ============ 128xBN GEMM, BK=32 ============
// MODE 0: BN=256, 3-buf (72KB, 2 blocks/CU), counted vmcnt(3) — proven 121 us (r13/r17).
// MODE 1: BN=128, 2-buf (32KB): 4 blocks/CU, grid 512 fully resident (r15 proven).
// NO XCD swizzle (r14: natural dispatch keeps A-panels L2-local; remap regressed).
template <int MODE>
__global__ __launch_bounds__(512, 4) void k_gemm_p(const bf16* __restrict__ A,
                                                   const bf16* __restrict__ Bt,
                                                   float* __restrict__ Cf,
                                                   bf16* __restrict__ qb,
                                                   bf16* __restrict__ kb,
                                                   bf16* __restrict__ vt,
                                                   const float* __restrict__ cost,
                                                   const float* __restrict__ sint) {
  constexpr int BN = (MODE == 1) ? 128 : 256;
  constexpr int NF = BN / 64;                    // col fragments per wave
  constexpr int NBUF = (MODE == 1) ? 2 : 3;
  constexpr int BSTRIDE = 8192 + BN * 64;        // bytes per LDS buffer
  extern __shared__ __align__(16) char smem[];
  const int tid = threadIdx.x;
  const int w = tid >> 6, lane = tid & 63;
  const int wm = w >> 2, wn = w & 3;
  const int lr = lane & 15, lg = lane >> 4;
  const int brow = blockIdx.x * 128, bcol = blockIdx.y * BN;

  f32x4 acc[4][NF] = {};

  auto stage = [&](int kt, int buf) {
    char* base = smem + buf * BSTRIDE;
    {  // A tile 128x32 (8KB): 1 load/thread
      const int row = tid >> 2, su = tid & 3;
      const int up = su ^ ((row >> 1) & 3);
      load_lds16(A + (size_t)(brow + row) * D_ + kt * 32 + up * 8, base + w * 1024);
    }
#pragma unroll
    for (int i = 0; i < BN / 128; ++i) {  // B tile BNx32: BN/128 loads/thread
      const int slot = i * 512 + tid;
      const int row = slot >> 2, su = slot & 3;
      const int up = su ^ ((row >> 1) & 3);
      load_lds16(Bt + (size_t)(bcol + row) * D_ + kt * 32 + up * 8,
                 base + 8192 + i * 8192 + w * 1024);
    }
  };

  const int NKT = D_ / 32;                       // 64
  if (MODE == 1) {
    stage(0, 0);
  } else {
    stage(0, 0); stage(1, 1);
  }
  int bs = 0;                                    // kt % NBUF
  for (int kt = 0; kt < NKT; ++kt) {
    if (MODE == 1) {
      asm volatile("s_waitcnt vmcnt(0)" ::: "memory");
    } else {
      if (kt < NKT - 1) asm volatile("s_waitcnt vmcnt(3)" ::: "memory");
      else              asm volatile("s_waitcnt vmcnt(0)" ::: "memory");
    }
    __builtin_amdgcn_s_barrier();                // raw: prefetch loads stay in flight
    __builtin_amdgcn_sched_barrier(0);
    if (MODE == 1) {
      if (kt + 1 < NKT) stage(kt + 1, (kt + 1) & 1);
    } else {
      if (kt + 2 < NKT) {
        int sb = bs + 2; if (sb >= 3) sb -= 3;
        stage(kt + 2, sb);
      }
    }

    const char* base = smem + bs * BSTRIDE;
    bf16x8 af[4], bf4[NF];
#pragma unroll
    for (int q = 0; q < 4; ++q) {
      const int r = wm * 64 + q * 16 + lr;
      af[q] = *(const bf16x8*)(base + r * 64 + ((lg ^ ((r >> 1) & 3)) * 16));
    }
#pragma unroll
    for (int nf = 0; nf < NF; ++nf) {
      const int r = wn * (NF * 16) + nf * 16 + lr;
      bf4[nf] = *(const bf16x8*)(base + 8192 + r * 64 + ((lg ^ ((r >> 1) & 3)) * 16));
    }
    __builtin_amdgcn_s_setprio(1);
#pragma unroll
    for (int q = 0; q < 4; ++q)
#pragma unroll
      for (int nf = 0; nf < NF; ++nf)
        acc[q][nf] = __builtin_amdgcn_mfma_f32_16x16x32_bf16(af[q], bf4[nf], acc[q][nf], 0, 0, 0);
    __builtin_amdgcn_s_setprio(0);
    bs = (bs == NBUF - 1) ? 0 : bs + 1;
  }

  if (MODE == 1) {
#pragma unroll
    for (int mf = 0; mf < 4; ++mf)
#pragma unroll
      for (int nf = 0; nf < NF; ++nf) {
        const int col = bcol + wn * (NF * 16) + nf * 16 + lr;
#pragma unroll
        for (int j = 0; j < 4; ++j) {
          const int row = brow + wm * 64 + mf * 16 + lg * 4 + j;
          Cf[(size_t)row * D_ + col] = acc[mf][nf][j];
        }
      }
  } else {
    const int t = bcol >> 11;                     // block-uniform (256 | 2048)
#pragma unroll
    for (int mf = 0; mf < 4; ++mf)
#pragma unroll
      for (int nf = 0; nf < NF; ++nf) {
        const int col = bcol + wn * (NF * 16) + nf * 16 + lr;
        const int h = (col >> 7) & (H_ - 1), mm = col & (HD_ - 1);
        if (t == 2) {
          const int row0 = brow + wm * 64 + mf * 16 + lg * 4;
          const int b = row0 >> 11, s0 = row0 & (S_ - 1);
          u16x4 pk;
#pragma unroll
          for (int j = 0; j < 4; ++j) pk[j] = f2bf_u(acc[mf][nf][j]);
          *(u16x4*)(vt + ((size_t)(b * H_ + h) * HD_ + mm) * S_ + s0) = pk;
        } else {
          const int i2 = mm >> 1;
          const bool odd = mm & 1;
#pragma unroll
          for (int j = 0; j < 4; ++j) {
            const int row = brow + wm * 64 + mf * 16 + lg * 4 + j;
            const int b = row >> 11, s = row & (S_ - 1);
            const float val = acc[mf][nf][j];
            const float part = __shfl_xor(val, 1, 64);   // col parity == lane parity
            const float c = cost[s * 64 + i2];
            const float sn = sint[s * 64 + i2];
            float o = odd ? (part * sn + val * c) : (val * c - part * sn);
            if (t == 0) o *= SCALE_;
            const int om = odd ? (64 + i2) : i2;
            bf16* dst = (t == 1) ? kb : qb;
            dst[((size_t)(b * H_ + h) * S_ + s) * HD_ + om] = __float2bfloat16(o);
          }
        }
      }
  }
}

// ---------------- flash attention: 512 threads, 8 waves x ONE 16-row group (round-16 exact) ----------------
// __expf softmax (known-fast intrinsic); l_run per-lane partial, cross-lane reduce deferred
// to the epilogue (r16 win). Raw s_barrier after explicit vmcnt(0).
__global__ __launch_bounds__(512, 4) void k_attn(const bf16* __restrict__ qb,
                                                 const bf16* __restrict__ kb,
                                                 const bf16* __restrict__ vt,
                                                 const int* __restrict__ mask,
                                                 bf16* __restrict__ attn_b) {
  const int tid = threadIdx.x, w = tid >> 6, lane = tid & 63;
  const int lr = lane & 15, lg = lane >> 4;
  const int qt = (blockIdx.y < 16) ? ((int)gridDim.x - 1 - (int)blockIdx.x)
                                   : (int)blockIdx.x;   // complementary CU pairing
  const int q0 = qt * 128;
  const int bh = blockIdx.y;
  const int b = bh >> 4, h = bh & (H_ - 1);
  const bf16* qp = qb + (size_t)bh * S_ * HD_;
  const bf16* kp = kb + (size_t)bh * S_ * HD_;
  const bf16* vp = vt + (size_t)bh * HD_ * S_;
  __shared__ __align__(16) bf16 Ks[2][64 * 128];   // 2 x 16 KB, XOR-swizzled rows
  __shared__ __align__(16) bf16 Vs[2][128 * 64];   // 2 x 16 KB, XOR-swizzled rows
  __shared__ __align__(16) bf16 Ps[8][16][40];     // per-wave half-P scratch

  const int qrow = q0 + w * 16 + lr;
  bf16x8 qf[4];
#pragma unroll
  for (int ks = 0; ks < 4; ++ks)
    qf[ks] = *(const bf16x8*)(qp + (size_t)qrow * HD_ + ks * 32 + lg * 8);

  float m_run[4], l_run[4];
  f32x4 oacc[8];
#pragma unroll
  for (int j = 0; j < 4; ++j) { m_run[j] = -INFINITY; l_run[j] = 0.f; }
#pragma unroll
  for (int c = 0; c < 8; ++c) oacc[c] = (f32x4)(0.f);

  auto stage = [&](int buf, int k0) {
#pragma unroll
    for (int i = 0; i < 2; ++i) {
      const int slot = i * 512 + tid;
      const int row = slot >> 4, j16 = slot & 15;
      load_lds16(kp + (size_t)(k0 + row) * HD_ + ((j16 ^ (row & 7)) * 8),
                 (char*)&Ks[buf][0] + i * 8192 + w * 1024);
    }
#pragma unroll
    for (int i = 0; i < 2; ++i) {
      const int slot = i * 512 + tid;
      const int row = slot >> 3, j8 = slot & 7;
      load_lds16(vp + (size_t)row * S_ + k0 + ((j8 ^ (row & 7)) * 8),
                 (char*)&Vs[buf][0] + i * 8192 + w * 1024);
    }
  };

  const int nt = 2 * qt + 2;
  stage(0, 0);
  asm volatile("s_waitcnt vmcnt(0)" ::: "memory");
  __builtin_amdgcn_s_barrier();
  __builtin_amdgcn_sched_barrier(0);

  int cur = 0;
  for (int it = 0; it < nt; ++it) {
    const int k0 = it * 64;
    if (it + 1 < nt) stage(cur ^ 1, k0 + 64);   // prefetch next tile (in flight across compute)

    // waves 0-3: rows q0+w*16..+15 all < q0+64 <= k0 on the last tile -> fully masked, skip
    const bool active = (it + 1 < nt) || (w >= 4);

    if (active) {
      int mk4[4];
#pragma unroll
      for (int n = 0; n < 4; ++n) mk4[n] = mask[b * S_ + k0 + n * 16 + lr];

      const bf16* ksb = &Ks[cur][0];
      const bf16* vsb = &Vs[cur][0];

      // QK^T: 16 q-rows x 64 k
      f32x4 sacc[4] = {};
      __builtin_amdgcn_s_setprio(1);
#pragma unroll
      for (int n = 0; n < 4; ++n) {
        const int krow = n * 16 + lr;
#pragma unroll
        for (int ks = 0; ks < 4; ++ks) {
          const int j16 = (ks * 4 + lg) ^ (krow & 7);
          const bf16x8 kf = *(const bf16x8*)(ksb + krow * 128 + j16 * 8);
          sacc[n] = __builtin_amdgcn_mfma_f32_16x16x32_bf16(qf[ks], kf, sacc[n], 0, 0, 0);
        }
      }
      __builtin_amdgcn_s_setprio(0);

      // mask + row max
      float mblk[4] = {-INFINITY, -INFINITY, -INFINITY, -INFINITY};
#pragma unroll
      for (int n = 0; n < 4; ++n) {
        const int kcol = k0 + n * 16 + lr;
#pragma unroll
        for (int j = 0; j < 4; ++j) {
          const int r = q0 + w * 16 + lg * 4 + j;
          float sv = sacc[n][j];
          const bool allowed = (kcol <= r) && (mk4[n] != 0 || kcol == r);
          sv = allowed ? sv : -1e9f;
          sacc[n][j] = sv;
          mblk[j] = fmaxf(mblk[j], sv);
        }
      }
#pragma unroll
      for (int xm = 1; xm < 16; xm <<= 1)
#pragma unroll
        for (int j = 0; j < 4; ++j)
          mblk[j] = fmaxf(mblk[j], __shfl_xor(mblk[j], xm, 64));

      // defer-max (T13); l_run is a per-lane partial, rescale is row-uniform
      bool grow = false;
#pragma unroll
      for (int j = 0; j < 4; ++j) grow = grow || (mblk[j] > m_run[j] + 8.f);
      if (__any(grow)) {
        float alpha[4];
#pragma unroll
        for (int j = 0; j < 4; ++j) {
          const float mn = fmaxf(m_run[j], mblk[j]);
          alpha[j] = __expf(m_run[j] - mn);
          m_run[j] = mn;
          l_run[j] *= alpha[j];
        }
#pragma unroll
        for (int c = 0; c < 8; ++c)
#pragma unroll
          for (int j = 0; j < 4; ++j) oacc[c][j] *= alpha[j];
      }

      // p = exp(s - m); accumulate per-lane l partials (NO per-iter cross-lane reduce)
#pragma unroll
      for (int n = 0; n < 4; ++n)
#pragma unroll
        for (int j = 0; j < 4; ++j) {
          const float p = __expf(sacc[n][j] - m_run[j]);
          l_run[j] += p;
          sacc[n][j] = p;
        }

      // PV in two 32-col halves through the per-wave half-P scratch (in-order reuse)
#pragma unroll
      for (int hh = 0; hh < 2; ++hh) {
#pragma unroll
        for (int n2 = 0; n2 < 2; ++n2)
#pragma unroll
          for (int j = 0; j < 4; ++j)
            Ps[w][lg * 4 + j][n2 * 16 + lr] = __float2bfloat16(sacc[hh * 2 + n2][j]);
        const bf16x8 pa = *(const bf16x8*)(&Ps[w][lr][lg * 8]);
        __builtin_amdgcn_s_setprio(1);
#pragma unroll
        for (int c = 0; c < 8; ++c) {
          const int vrow = c * 16 + lr;
          const int unit = (hh * 4 + lg) ^ (vrow & 7);
          const bf16x8 vf = *(const bf16x8*)(vsb + vrow * 64 + unit * 8);
          oacc[c] = __builtin_amdgcn_mfma_f32_16x16x32_bf16(pa, vf, oacc[c], 0, 0, 0);
        }
        __builtin_amdgcn_s_setprio(0);
      }
    }

    asm volatile("s_waitcnt vmcnt(0)" ::: "memory");  // next tile staged (all waves)
    __builtin_amdgcn_s_barrier();                      // raw: no redundant re-drain
    __builtin_amdgcn_sched_barrier(0);
    cur ^= 1;
  }

  // epilogue: single cross-lane l reduce, then normalize and write attn_b [B,S,H*hd] bf16
#pragma unroll
  for (int xm = 1; xm < 16; xm <<= 1)
#pragma unroll
    for (int j = 0; j < 4; ++j)
      l_run[j] += __shfl_xor(l_run[j], xm, 64);
#pragma unroll
  for (int j = 0; j < 4; ++j) {
    const float inv = 1.f / l_run[j];
    const int r = q0 + w * 16 + lg * 4 + j;
#pragma unroll
    for (int c = 0; c < 8; ++c)
      attn_b[(size_t)(b * S_ + r) * D_ + h * HD_ + c * 16 + lr] =
          __float2bfloat16(oacc[c][j] * inv);
  }
}

extern "C" void kernel_launch(void* const* d_in, const int* in_sizes, int n_in,
                              void* d_out, int out_size, void* d_ws, size_t ws_size,
                              hipStream_t stream) {
  (void)in_sizes; (void)n_in; (void)out_size; (void)ws_size;
  const float* x        = (const float*)d_in[0];
  const int*   attn_mask= (const int*)d_in[1];
  const float* in_proj  = (const float*)d_in[2];
  const float* out_proj = (const float*)d_in[3];
  float* out = (float*)d_out;
  char* ws = (char*)d_ws;

  bf16*  xb    = (bf16*)(ws + 0);            // 16 MB (also attn_b later)
  bf16*  wqkvT = (bf16*)(ws + 16777216);     // 24 MB  ([3][2048][2048] = [6144][2048])
  bf16*  woT   = (bf16*)(ws + 41943040);     //  8 MB
  float* cost  = (float*)(ws + 50331648);
  float* sint  = (float*)(ws + 50855936);
  bf16*  vt    = (bf16*)(ws + 51380224);     // 16 MB
  bf16* qb = (bf16*)d_out;                   // d_out as scratch (dead before final GEMM)
  bf16* kb = (bf16*)((char*)d_out + 16777216);
  bf16* attn_b = xb;

  // allow dynamic LDS (host-side, graph-capture safe)
  static int lds_ok = 0;
  if (!lds_ok) {
    (void)hipFuncSetAttribute((const void*)k_gemm_p<0>,
                              hipFuncAttributeMaxDynamicSharedMemorySize, 73728);
    (void)hipFuncSetAttribute((const void*)k_gemm_p<1>,
                              hipFuncAttributeMaxDynamicSharedMemorySize, 32768);
    lds_ok = 1;
  }

  k_prep<<<8704, 256, 0, stream>>>(x, xb, in_proj, wqkvT, out_proj, woT, cost, sint);
  k_gemm_p<0><<<dim3(32, 24), 512, 73728, stream>>>(xb, wqkvT, nullptr, qb, kb, vt, cost, sint);
  k_attn<<<dim3(16, 32), 512, 0, stream>>>(qb, kb, vt, attn_mask, attn_b);
  k_gemm_p<1><<<dim3(32, 16), 512, 32768, stream>>>(attn_b, woT, out, nullptr, nullptr, nullptr,
                                                    nullptr, nullptr);
}

// Round 19
// 263.733 us; speedup vs baseline: 1.0429x; 1.0214x over previous
//
#include <hip/hip_runtime.h>
#include <hip/hip_bf16.h>

#define B_   2
#define S_   2048
#define H_   16
#define HD_  128
#define D_   2048
#define BS_  4096
#define SCALE_ 0.08838834764831845f   // 1/sqrt(128), applied in QKV epilogue (t==0)

typedef __hip_bfloat16 bf16;
typedef float f32x4 __attribute__((ext_vector_type(4)));
typedef __bf16 bf16x8 __attribute__((ext_vector_type(8)));
typedef unsigned short u16x8 __attribute__((ext_vector_type(8)));
typedef unsigned short u16x4 __attribute__((ext_vector_type(4)));

static __device__ __forceinline__ unsigned short f2bf_u(float f) {
  bf16 h = __float2bfloat16(f);
  return __builtin_bit_cast(unsigned short, h);
}
static __device__ __forceinline__ void load_lds16(const void* g, void* l) {
  __builtin_amdgcn_global_load_lds((const __attribute__((address_space(1))) void*)g,
                                   (__attribute__((address_space(3))) void*)l, 16, 0, 0);
}

// ---------------- fused prep: convert x | transpose weights | rope tables ----------------
__global__ __launch_bounds__(256) void k_prep(const float* __restrict__ x,
                                              bf16* __restrict__ xb,
                                              const float* __restrict__ in_proj,
                                              bf16* __restrict__ wqkvT,
                                              const float* __restrict__ out_proj,
                                              bf16* __restrict__ woT,
                                              float* __restrict__ cost,
                                              float* __restrict__ sint) {
  __shared__ float tile[64][65];
  const int bid = blockIdx.x;
  const int t = threadIdx.x;
  if (bid < 4096) {
    const size_t i = ((size_t)bid * 256 + t) * 8;
    const float4 a = *(const float4*)(x + i);
    const float4 b = *(const float4*)(x + i + 4);
    u16x8 o;
    o[0] = f2bf_u(a.x); o[1] = f2bf_u(a.y); o[2] = f2bf_u(a.z); o[3] = f2bf_u(a.w);
    o[4] = f2bf_u(b.x); o[5] = f2bf_u(b.y); o[6] = f2bf_u(b.z); o[7] = f2bf_u(b.w);
    *(u16x8*)(xb + i) = o;
  } else if (bid < 8192) {
    const int local = bid - 4096;
    const float* src;
    bf16* dst;
    if (local < 3072) {
      const int z = local >> 10;
      src = in_proj + (size_t)z * D_ * D_;
      dst = wqkvT + (size_t)z * D_ * D_;
    } else {
      src = out_proj;
      dst = woT;
    }
    const int rem = local & 1023;
    const int x0 = (rem & 31) * 64, y0 = (rem >> 5) * 64;
#pragma unroll
    for (int i = 0; i < 16; ++i) {
      int idx = t + i * 256, r = idx >> 6, c = idx & 63;
      tile[r][c] = src[(size_t)(y0 + r) * D_ + x0 + c];
    }
    __syncthreads();
#pragma unroll
    for (int i = 0; i < 16; ++i) {
      int idx = t + i * 256, c = idx >> 6, r = idx & 63;
      dst[(size_t)(x0 + c) * D_ + y0 + r] = __float2bfloat16(tile[r][c]);
    }
  } else {
    const int idx = (bid - 8192) * 256 + t;   // S_*64 total
    const int s = idx >> 6, d = idx & 63;
    const float inv = expf(-(float)d * (9.210340371976184f / 64.f)); // 10000^(-d/64)
    const float ang = (float)s * inv;
    cost[idx] = cosf(ang);
    sint[idx] = sinf(ang);
  }
}

// ============ 128xBN GEMM, BK=32 ============
// MODE 0: BN=256, 3-buf (72KB, 2 blocks/CU), counted vmcnt(3) — proven 121 us (r13/r17).
//         Round-19: epilogue bounces q/k/v through LDS (dead after K-loop) so all global
//         writes are coalesced 16B stores (was 64 scalar 2B stores/thread for q/k).
// MODE 1: BN=128, 2-buf (32KB): 4 blocks/CU, grid 512 fully resident (r15 proven).
// NO XCD swizzle (r14: natural dispatch keeps A-panels L2-local; remap regressed).
template <int MODE>
__global__ __launch_bounds__(512, 4) void k_gemm_p(const bf16* __restrict__ A,
                                                   const bf16* __restrict__ Bt,
                                                   float* __restrict__ Cf,
                                                   bf16* __restrict__ qb,
                                                   bf16* __restrict__ kb,
                                                   bf16* __restrict__ vt,
                                                   const float* __restrict__ cost,
                                                   const float* __restrict__ sint) {
  constexpr int BN = (MODE == 1) ? 128 : 256;
  constexpr int NF = BN / 64;                    // col fragments per wave
  constexpr int NBUF = (MODE == 1) ? 2 : 3;
  constexpr int BSTRIDE = 8192 + BN * 64;        // bytes per LDS buffer
  extern __shared__ __align__(16) char smem[];
  const int tid = threadIdx.x;
  const int w = tid >> 6, lane = tid & 63;
  const int wm = w >> 2, wn = w & 3;
  const int lr = lane & 15, lg = lane >> 4;
  const int brow = blockIdx.x * 128, bcol = blockIdx.y * BN;

  f32x4 acc[4][NF] = {};

  auto stage = [&](int kt, int buf) {
    char* base = smem + buf * BSTRIDE;
    {  // A tile 128x32 (8KB): 1 load/thread
      const int row = tid >> 2, su = tid & 3;
      const int up = su ^ ((row >> 1) & 3);
      load_lds16(A + (size_t)(brow + row) * D_ + kt * 32 + up * 8, base + w * 1024);
    }
#pragma unroll
    for (int i = 0; i < BN / 128; ++i) {  // B tile BNx32: BN/128 loads/thread
      const int slot = i * 512 + tid;
      const int row = slot >> 2, su = slot & 3;
      const int up = su ^ ((row >> 1) & 3);
      load_lds16(Bt + (size_t)(bcol + row) * D_ + kt * 32 + up * 8,
                 base + 8192 + i * 8192 + w * 1024);
    }
  };

  const int NKT = D_ / 32;                       // 64
  if (MODE == 1) {
    stage(0, 0);
  } else {
    stage(0, 0); stage(1, 1);
  }
  int bs = 0;                                    // kt % NBUF
  for (int kt = 0; kt < NKT; ++kt) {
    if (MODE == 1) {
      asm volatile("s_waitcnt vmcnt(0)" ::: "memory");
    } else {
      if (kt < NKT - 1) asm volatile("s_waitcnt vmcnt(3)" ::: "memory");
      else              asm volatile("s_waitcnt vmcnt(0)" ::: "memory");
    }
    __builtin_amdgcn_s_barrier();                // raw: prefetch loads stay in flight
    __builtin_amdgcn_sched_barrier(0);
    if (MODE == 1) {
      if (kt + 1 < NKT) stage(kt + 1, (kt + 1) & 1);
    } else {
      if (kt + 2 < NKT) {
        int sb = bs + 2; if (sb >= 3) sb -= 3;
        stage(kt + 2, sb);
      }
    }

    const char* base = smem + bs * BSTRIDE;
    bf16x8 af[4], bf4[NF];
#pragma unroll
    for (int q = 0; q < 4; ++q) {
      const int r = wm * 64 + q * 16 + lr;
      af[q] = *(const bf16x8*)(base + r * 64 + ((lg ^ ((r >> 1) & 3)) * 16));
    }
#pragma unroll
    for (int nf = 0; nf < NF; ++nf) {
      const int r = wn * (NF * 16) + nf * 16 + lr;
      bf4[nf] = *(const bf16x8*)(base + 8192 + r * 64 + ((lg ^ ((r >> 1) & 3)) * 16));
    }
    __builtin_amdgcn_s_setprio(1);
#pragma unroll
    for (int q = 0; q < 4; ++q)
#pragma unroll
      for (int nf = 0; nf < NF; ++nf)
        acc[q][nf] = __builtin_amdgcn_mfma_f32_16x16x32_bf16(af[q], bf4[nf], acc[q][nf], 0, 0, 0);
    __builtin_amdgcn_s_setprio(0);
    bs = (bs == NBUF - 1) ? 0 : bs + 1;
  }

  if (MODE == 1) {
#pragma unroll
    for (int mf = 0; mf < 4; ++mf)
#pragma unroll
      for (int nf = 0; nf < NF; ++nf) {
        const int col = bcol + wn * (NF * 16) + nf * 16 + lr;
#pragma unroll
        for (int j = 0; j < 4; ++j) {
          const int row = brow + wm * 64 + mf * 16 + lg * 4 + j;
          Cf[(size_t)row * D_ + col] = acc[mf][nf][j];
        }
      }
  } else {
    const int t = bcol >> 11;                     // block-uniform (256 | 2048)
    const int b = brow >> 11, sbase = brow & (S_ - 1);
    __syncthreads();                              // main-loop LDS dead across ALL waves
    bf16* eb = (bf16*)smem;
    if (t == 2) {
      // v: LDS tile [cc 256][rr 128] pitch 136 (272B rows: 16B-aligned, ~2-way write bank)
#pragma unroll
      for (int mf = 0; mf < 4; ++mf)
#pragma unroll
        for (int nf = 0; nf < NF; ++nf) {
          const int cc = wn * (NF * 16) + nf * 16 + lr;
          const int rr0 = wm * 64 + mf * 16 + lg * 4;
          u16x4 pk;
#pragma unroll
          for (int j = 0; j < 4; ++j) pk[j] = f2bf_u(acc[mf][nf][j]);
          *(u16x4*)(eb + cc * 136 + rr0) = pk;
        }
      __syncthreads();
      // readout: 256x128 els = 4096 16B-chunks, 8/thread, fully coalesced stores
#pragma unroll
      for (int i = 0; i < 8; ++i) {
        const int ch = i * 512 + tid;
        const int cc = ch >> 4, sc = (ch & 15) * 8;
        const bf16x8 v = *(const bf16x8*)(eb + cc * 136 + sc);
        const int h = ((bcol & (D_ - 1)) >> 7) + (cc >> 7);
        const int mm = cc & (HD_ - 1);
        *(bf16x8*)(vt + ((size_t)(b * H_ + h) * HD_ + mm) * S_ + sbase + sc) = v;
      }
    } else {
      // q/k with RoPE: LDS tile [rr 128][oc 256] pitch 264 (528B rows: 16B-aligned)
#pragma unroll
      for (int mf = 0; mf < 4; ++mf)
#pragma unroll
        for (int nf = 0; nf < NF; ++nf) {
          const int cc = wn * (NF * 16) + nf * 16 + lr;
          const int hh = cc >> 7, mm = cc & (HD_ - 1);
          const int i2 = mm >> 1;
          const bool odd = mm & 1;
          const int oc = hh * 128 + (odd ? (64 + i2) : i2);
#pragma unroll
          for (int j = 0; j < 4; ++j) {
            const int rr = wm * 64 + mf * 16 + lg * 4 + j;
            const int s = sbase + rr;
            const float val = acc[mf][nf][j];
            const float part = __shfl_xor(val, 1, 64);   // col parity == lane parity
            const float c = cost[s * 64 + i2];
            const float sn = sint[s * 64 + i2];
            float o = odd ? (part * sn + val * c) : (val * c - part * sn);
            if (t == 0) o *= SCALE_;
            eb[rr * 264 + oc] = __float2bfloat16(o);
          }
        }
      __syncthreads();
      bf16* dst = (t == 1) ? kb : qb;
      // readout: 128x256 els = 4096 16B-chunks, 8/thread, fully coalesced stores
#pragma unroll
      for (int i = 0; i < 8; ++i) {
        const int ch = i * 512 + tid;
        const int rr = ch >> 5, oc0 = (ch & 31) * 8;
        const bf16x8 v = *(const bf16x8*)(eb + rr * 264 + oc0);
        const int h = ((bcol & (D_ - 1)) >> 7) + (oc0 >> 7);
        const int om0 = oc0 & (HD_ - 1);
        *(bf16x8*)(dst + ((size_t)(b * H_ + h) * S_ + sbase + rr) * HD_ + om0) = v;
      }
    }
  }
}

// ---------------- flash attention: 512 threads, 8 waves x ONE 16-row group (round-18 exact) ----------------
__global__ __launch_bounds__(512, 4) void k_attn(const bf16* __restrict__ qb,
                                                 const bf16* __restrict__ kb,
                                                 const bf16* __restrict__ vt,
                                                 const int* __restrict__ mask,
                                                 bf16* __restrict__ attn_b) {
  const int tid = threadIdx.x, w = tid >> 6, lane = tid & 63;
  const int lr = lane & 15, lg = lane >> 4;
  const int qt = (blockIdx.y < 16) ? ((int)gridDim.x - 1 - (int)blockIdx.x)
                                   : (int)blockIdx.x;   // complementary CU pairing
  const int q0 = qt * 128;
  const int bh = blockIdx.y;
  const int b = bh >> 4, h = bh & (H_ - 1);
  const bf16* qp = qb + (size_t)bh * S_ * HD_;
  const bf16* kp = kb + (size_t)bh * S_ * HD_;
  const bf16* vp = vt + (size_t)bh * HD_ * S_;
  __shared__ __align__(16) bf16 Ks[2][64 * 128];   // 2 x 16 KB, XOR-swizzled rows
  __shared__ __align__(16) bf16 Vs[2][128 * 64];   // 2 x 16 KB, XOR-swizzled rows
  __shared__ __align__(16) bf16 Ps[8][16][40];     // per-wave half-P scratch

  const int qrow = q0 + w * 16 + lr;
  bf16x8 qf[4];
#pragma unroll
  for (int ks = 0; ks < 4; ++ks)
    qf[ks] = *(const bf16x8*)(qp + (size_t)qrow * HD_ + ks * 32 + lg * 8);

  float m_run[4], l_run[4];
  f32x4 oacc[8];
#pragma unroll
  for (int j = 0; j < 4; ++j) { m_run[j] = -INFINITY; l_run[j] = 0.f; }
#pragma unroll
  for (int c = 0; c < 8; ++c) oacc[c] = (f32x4)(0.f);

  auto stage = [&](int buf, int k0) {
#pragma unroll
    for (int i = 0; i < 2; ++i) {
      const int slot = i * 512 + tid;
      const int row = slot >> 4, j16 = slot & 15;
      load_lds16(kp + (size_t)(k0 + row) * HD_ + ((j16 ^ (row & 7)) * 8),
                 (char*)&Ks[buf][0] + i * 8192 + w * 1024);
    }
#pragma unroll
    for (int i = 0; i < 2; ++i) {
      const int slot = i * 512 + tid;
      const int row = slot >> 3, j8 = slot & 7;
      load_lds16(vp + (size_t)row * S_ + k0 + ((j8 ^ (row & 7)) * 8),
                 (char*)&Vs[buf][0] + i * 8192 + w * 1024);
    }
  };

  const int nt = 2 * qt + 2;
  stage(0, 0);
  asm volatile("s_waitcnt vmcnt(0)" ::: "memory");
  __builtin_amdgcn_s_barrier();
  __builtin_amdgcn_sched_barrier(0);

  int cur = 0;
  for (int it = 0; it < nt; ++it) {
    const int k0 = it * 64;
    if (it + 1 < nt) stage(cur ^ 1, k0 + 64);   // prefetch next tile (in flight across compute)

    // waves 0-3: rows q0+w*16..+15 all < q0+64 <= k0 on the last tile -> fully masked, skip
    const bool active = (it + 1 < nt) || (w >= 4);

    if (active) {
      int mk4[4];
#pragma unroll
      for (int n = 0; n < 4; ++n) mk4[n] = mask[b * S_ + k0 + n * 16 + lr];

      const bf16* ksb = &Ks[cur][0];
      const bf16* vsb = &Vs[cur][0];

      // QK^T: 16 q-rows x 64 k
      f32x4 sacc[4] = {};
      __builtin_amdgcn_s_setprio(1);
#pragma unroll
      for (int n = 0; n < 4; ++n) {
        const int krow = n * 16 + lr;
#pragma unroll
        for (int ks = 0; ks < 4; ++ks) {
          const int j16 = (ks * 4 + lg) ^ (krow & 7);
          const bf16x8 kf = *(const bf16x8*)(ksb + krow * 128 + j16 * 8);
          sacc[n] = __builtin_amdgcn_mfma_f32_16x16x32_bf16(qf[ks], kf, sacc[n], 0, 0, 0);
        }
      }
      __builtin_amdgcn_s_setprio(0);

      // mask + row max
      float mblk[4] = {-INFINITY, -INFINITY, -INFINITY, -INFINITY};
#pragma unroll
      for (int n = 0; n < 4; ++n) {
        const int kcol = k0 + n * 16 + lr;
#pragma unroll
        for (int j = 0; j < 4; ++j) {
          const int r = q0 + w * 16 + lg * 4 + j;
          float sv = sacc[n][j];
          const bool allowed = (kcol <= r) && (mk4[n] != 0 || kcol == r);
          sv = allowed ? sv : -1e9f;
          sacc[n][j] = sv;
          mblk[j] = fmaxf(mblk[j], sv);
        }
      }
#pragma unroll
      for (int xm = 1; xm < 16; xm <<= 1)
#pragma unroll
        for (int j = 0; j < 4; ++j)
          mblk[j] = fmaxf(mblk[j], __shfl_xor(mblk[j], xm, 64));

      // defer-max (T13); l_run is a per-lane partial, rescale is row-uniform
      bool grow = false;
#pragma unroll
      for (int j = 0; j < 4; ++j) grow = grow || (mblk[j] > m_run[j] + 8.f);
      if (__any(grow)) {
        float alpha[4];
#pragma unroll
        for (int j = 0; j < 4; ++j) {
          const float mn = fmaxf(m_run[j], mblk[j]);
          alpha[j] = __expf(m_run[j] - mn);
          m_run[j] = mn;
          l_run[j] *= alpha[j];
        }
#pragma unroll
        for (int c = 0; c < 8; ++c)
#pragma unroll
          for (int j = 0; j < 4; ++j) oacc[c][j] *= alpha[j];
      }

      // p = exp(s - m); accumulate per-lane l partials (NO per-iter cross-lane reduce)
#pragma unroll
      for (int n = 0; n < 4; ++n)
#pragma unroll
        for (int j = 0; j < 4; ++j) {
          const float p = __expf(sacc[n][j] - m_run[j]);
          l_run[j] += p;
          sacc[n][j] = p;
        }

      // PV in two 32-col halves through the per-wave half-P scratch (in-order reuse)
#pragma unroll
      for (int hh = 0; hh < 2; ++hh) {
#pragma unroll
        for (int n2 = 0; n2 < 2; ++n2)
#pragma unroll
          for (int j = 0; j < 4; ++j)
            Ps[w][lg * 4 + j][n2 * 16 + lr] = __float2bfloat16(sacc[hh * 2 + n2][j]);
        const bf16x8 pa = *(const bf16x8*)(&Ps[w][lr][lg * 8]);
        __builtin_amdgcn_s_setprio(1);
#pragma unroll
        for (int c = 0; c < 8; ++c) {
          const int vrow = c * 16 + lr;
          const int unit = (hh * 4 + lg) ^ (vrow & 7);
          const bf16x8 vf = *(const bf16x8*)(vsb + vrow * 64 + unit * 8);
          oacc[c] = __builtin_amdgcn_mfma_f32_16x16x32_bf16(pa, vf, oacc[c], 0, 0, 0);
        }
        __builtin_amdgcn_s_setprio(0);
      }
    }

    asm volatile("s_waitcnt vmcnt(0)" ::: "memory");  // next tile staged (all waves)
    __builtin_amdgcn_s_barrier();                      // raw: no redundant re-drain
    __builtin_amdgcn_sched_barrier(0);
    cur ^= 1;
  }

  // epilogue: single cross-lane l reduce, then normalize and write attn_b [B,S,H*hd] bf16
#pragma unroll
  for (int xm = 1; xm < 16; xm <<= 1)
#pragma unroll
    for (int j = 0; j < 4; ++j)
      l_run[j] += __shfl_xor(l_run[j], xm, 64);
#pragma unroll
  for (int j = 0; j < 4; ++j) {
    const float inv = 1.f / l_run[j];
    const int r = q0 + w * 16 + lg * 4 + j;
#pragma unroll
    for (int c = 0; c < 8; ++c)
      attn_b[(size_t)(b * S_ + r) * D_ + h * HD_ + c * 16 + lr] =
          __float2bfloat16(oacc[c][j] * inv);
  }
}

extern "C" void kernel_launch(void* const* d_in, const int* in_sizes, int n_in,
                              void* d_out, int out_size, void* d_ws, size_t ws_size,
                              hipStream_t stream) {
  (void)in_sizes; (void)n_in; (void)out_size; (void)ws_size;
  const float* x        = (const float*)d_in[0];
  const int*   attn_mask= (const int*)d_in[1];
  const float* in_proj  = (const float*)d_in[2];
  const float* out_proj = (const float*)d_in[3];
  float* out = (float*)d_out;
  char* ws = (char*)d_ws;

  bf16*  xb    = (bf16*)(ws + 0);            // 16 MB (also attn_b later)
  bf16*  wqkvT = (bf16*)(ws + 16777216);     // 24 MB  ([3][2048][2048] = [6144][2048])
  bf16*  woT   = (bf16*)(ws + 41943040);     //  8 MB
  float* cost  = (float*)(ws + 50331648);
  float* sint  = (float*)(ws + 50855936);
  bf16*  vt    = (bf16*)(ws + 51380224);     // 16 MB
  bf16* qb = (bf16*)d_out;                   // d_out as scratch (dead before final GEMM)
  bf16* kb = (bf16*)((char*)d_out + 16777216);
  bf16* attn_b = xb;

  // allow dynamic LDS (host-side, graph-capture safe)
  static int lds_ok = 0;
  if (!lds_ok) {
    (void)hipFuncSetAttribute((const void*)k_gemm_p<0>,
                              hipFuncAttributeMaxDynamicSharedMemorySize, 73728);
    (void)hipFuncSetAttribute((const void*)k_gemm_p<1>,
                              hipFuncAttributeMaxDynamicSharedMemorySize, 32768);
    lds_ok = 1;
  }

  k_prep<<<8704, 256, 0, stream>>>(x, xb, in_proj, wqkvT, out_proj, woT, cost, sint);
  k_gemm_p<0><<<dim3(32, 24), 512, 73728, stream>>>(xb, wqkvT, nullptr, qb, kb, vt, cost, sint);
  k_attn<<<dim3(16, 32), 512, 0, stream>>>(qb, kb, vt, attn_mask, attn_b);
  k_gemm_p<1><<<dim3(32, 16), 512, 32768, stream>>>(attn_b, woT, out, nullptr, nullptr, nullptr,
                                                    nullptr, nullptr);
}

// Round 20
// 263.638 us; speedup vs baseline: 1.0433x; 1.0004x over previous
//
#include <hip/hip_runtime.h>
#include <hip/hip_bf16.h>

#define B_   2
#define S_   2048
#define H_   16
#define HD_  128
#define D_   2048
#define BS_  4096
#define SCALE_ 0.08838834764831845f   // 1/sqrt(128), applied in QKV epilogue (t==0)

typedef __hip_bfloat16 bf16;
typedef float f32x4 __attribute__((ext_vector_type(4)));
typedef __bf16 bf16x8 __attribute__((ext_vector_type(8)));
typedef unsigned short u16x8 __attribute__((ext_vector_type(8)));
typedef unsigned short u16x4 __attribute__((ext_vector_type(4)));

static __device__ __forceinline__ unsigned short f2bf_u(float f) {
  bf16 h = __float2bfloat16(f);
  return __builtin_bit_cast(unsigned short, h);
}
static __device__ __forceinline__ void load_lds16(const void* g, void* l) {
  __builtin_amdgcn_global_load_lds((const __attribute__((address_space(1))) void*)g,
                                   (__attribute__((address_space(3))) void*)l, 16, 0, 0);
}

// ---------------- fused prep: convert x | transpose weights | rope tables ----------------
// Round-20: transpose write-back vectorized (u16x8, 2 stores/thread instead of 16 scalar).
__global__ __launch_bounds__(256) void k_prep(const float* __restrict__ x,
                                              bf16* __restrict__ xb,
                                              const float* __restrict__ in_proj,
                                              bf16* __restrict__ wqkvT,
                                              const float* __restrict__ out_proj,
                                              bf16* __restrict__ woT,
                                              float* __restrict__ cost,
                                              float* __restrict__ sint) {
  __shared__ float tile[64][65];
  const int bid = blockIdx.x;
  const int t = threadIdx.x;
  if (bid < 4096) {
    const size_t i = ((size_t)bid * 256 + t) * 8;
    const float4 a = *(const float4*)(x + i);
    const float4 b = *(const float4*)(x + i + 4);
    u16x8 o;
    o[0] = f2bf_u(a.x); o[1] = f2bf_u(a.y); o[2] = f2bf_u(a.z); o[3] = f2bf_u(a.w);
    o[4] = f2bf_u(b.x); o[5] = f2bf_u(b.y); o[6] = f2bf_u(b.z); o[7] = f2bf_u(b.w);
    *(u16x8*)(xb + i) = o;
  } else if (bid < 8192) {
    const int local = bid - 4096;
    const float* src;
    bf16* dst;
    if (local < 3072) {
      const int z = local >> 10;
      src = in_proj + (size_t)z * D_ * D_;
      dst = wqkvT + (size_t)z * D_ * D_;
    } else {
      src = out_proj;
      dst = woT;
    }
    const int rem = local & 1023;
    const int x0 = (rem & 31) * 64, y0 = (rem >> 5) * 64;
#pragma unroll
    for (int i = 0; i < 16; ++i) {
      int idx = t + i * 256, r = idx >> 6, c = idx & 63;
      tile[r][c] = src[(size_t)(y0 + r) * D_ + x0 + c];
    }
    __syncthreads();
    // vectorized write-back: 512 16B chunks (8 per dst row), 2 per thread
#pragma unroll
    for (int i = 0; i < 2; ++i) {
      const int ch = i * 256 + t;
      const int c = ch >> 3;            // dst row = x0 + c
      const int r0 = (ch & 7) * 8;      // 8 source rows -> 8 consecutive dst cols
      u16x8 v;
#pragma unroll
      for (int j = 0; j < 8; ++j) v[j] = f2bf_u(tile[r0 + j][c]);
      *(u16x8*)(dst + (size_t)(x0 + c) * D_ + y0 + r0) = v;
    }
  } else {
    const int idx = (bid - 8192) * 256 + t;   // S_*64 total
    const int s = idx >> 6, d = idx & 63;
    const float inv = expf(-(float)d * (9.210340371976184f / 64.f)); // 10000^(-d/64)
    const float ang = (float)s * inv;
    cost[idx] = cosf(ang);
    sint[idx] = sinf(ang);
  }
}

// ============ 128xBN GEMM, BK=32 ============
// MODE 0: BN=256, 3-buf (72KB, 2 blocks/CU), counted vmcnt(3); LDS-bounced coalesced epilogue
//         with fused RoPE (r19: 121->114 us, MfmaUtil 40%).
// MODE 1: BN=128, 2-buf (32KB), 4 blocks/CU; r20: fp32 C epilogue bounced through LDS in two
//         64-row halves -> 8 f32x4 coalesced stores/thread (was 32 scalar dword stores).
// NO XCD swizzle (r14: natural dispatch keeps A-panels L2-local; remap regressed).
template <int MODE>
__global__ __launch_bounds__(512, 4) void k_gemm_p(const bf16* __restrict__ A,
                                                   const bf16* __restrict__ Bt,
                                                   float* __restrict__ Cf,
                                                   bf16* __restrict__ qb,
                                                   bf16* __restrict__ kb,
                                                   bf16* __restrict__ vt,
                                                   const float* __restrict__ cost,
                                                   const float* __restrict__ sint) {
  constexpr int BN = (MODE == 1) ? 128 : 256;
  constexpr int NF = BN / 64;                    // col fragments per wave
  constexpr int NBUF = (MODE == 1) ? 2 : 3;
  constexpr int BSTRIDE = 8192 + BN * 64;        // bytes per LDS buffer
  extern __shared__ __align__(16) char smem[];
  const int tid = threadIdx.x;
  const int w = tid >> 6, lane = tid & 63;
  const int wm = w >> 2, wn = w & 3;
  const int lr = lane & 15, lg = lane >> 4;
  const int brow = blockIdx.x * 128, bcol = blockIdx.y * BN;

  f32x4 acc[4][NF] = {};

  auto stage = [&](int kt, int buf) {
    char* base = smem + buf * BSTRIDE;
    {  // A tile 128x32 (8KB): 1 load/thread
      const int row = tid >> 2, su = tid & 3;
      const int up = su ^ ((row >> 1) & 3);
      load_lds16(A + (size_t)(brow + row) * D_ + kt * 32 + up * 8, base + w * 1024);
    }
#pragma unroll
    for (int i = 0; i < BN / 128; ++i) {  // B tile BNx32: BN/128 loads/thread
      const int slot = i * 512 + tid;
      const int row = slot >> 2, su = slot & 3;
      const int up = su ^ ((row >> 1) & 3);
      load_lds16(Bt + (size_t)(bcol + row) * D_ + kt * 32 + up * 8,
                 base + 8192 + i * 8192 + w * 1024);
    }
  };

  const int NKT = D_ / 32;                       // 64
  if (MODE == 1) {
    stage(0, 0);
  } else {
    stage(0, 0); stage(1, 1);
  }
  int bs = 0;                                    // kt % NBUF
  for (int kt = 0; kt < NKT; ++kt) {
    if (MODE == 1) {
      asm volatile("s_waitcnt vmcnt(0)" ::: "memory");
    } else {
      if (kt < NKT - 1) asm volatile("s_waitcnt vmcnt(3)" ::: "memory");
      else              asm volatile("s_waitcnt vmcnt(0)" ::: "memory");
    }
    __builtin_amdgcn_s_barrier();                // raw: prefetch loads stay in flight
    __builtin_amdgcn_sched_barrier(0);
    if (MODE == 1) {
      if (kt + 1 < NKT) stage(kt + 1, (kt + 1) & 1);
    } else {
      if (kt + 2 < NKT) {
        int sb = bs + 2; if (sb >= 3) sb -= 3;
        stage(kt + 2, sb);
      }
    }

    const char* base = smem + bs * BSTRIDE;
    bf16x8 af[4], bf4[NF];
#pragma unroll
    for (int q = 0; q < 4; ++q) {
      const int r = wm * 64 + q * 16 + lr;
      af[q] = *(const bf16x8*)(base + r * 64 + ((lg ^ ((r >> 1) & 3)) * 16));
    }
#pragma unroll
    for (int nf = 0; nf < NF; ++nf) {
      const int r = wn * (NF * 16) + nf * 16 + lr;
      bf4[nf] = *(const bf16x8*)(base + 8192 + r * 64 + ((lg ^ ((r >> 1) & 3)) * 16));
    }
    __builtin_amdgcn_s_setprio(1);
#pragma unroll
    for (int q = 0; q < 4; ++q)
#pragma unroll
      for (int nf = 0; nf < NF; ++nf)
        acc[q][nf] = __builtin_amdgcn_mfma_f32_16x16x32_bf16(af[q], bf4[nf], acc[q][nf], 0, 0, 0);
    __builtin_amdgcn_s_setprio(0);
    bs = (bs == NBUF - 1) ? 0 : bs + 1;
  }

  if (MODE == 1) {
    // fp32 C epilogue via LDS bounce: two 64-row halves, [64][132] f32 tile (pad -> <=2-way)
    float* ebf = (float*)smem;
#pragma unroll
    for (int half = 0; half < 2; ++half) {
      __syncthreads();                 // main-loop LDS / prior-half reads complete
      if (wm == half) {
#pragma unroll
        for (int mf = 0; mf < 4; ++mf)
#pragma unroll
          for (int nf = 0; nf < NF; ++nf) {
            const int lcol = wn * (NF * 16) + nf * 16 + lr;
#pragma unroll
            for (int j = 0; j < 4; ++j) {
              const int lrow = mf * 16 + lg * 4 + j;
              ebf[lrow * 132 + lcol] = acc[mf][nf][j];
            }
          }
      }
      __syncthreads();
      // readout: 64x128 f32 = 2048 16B chunks, 4/thread, 512B-contiguous row segments
#pragma unroll
      for (int i = 0; i < 4; ++i) {
        const int ch = i * 512 + tid;
        const int rr = ch >> 5, cc = ch & 31;
        const f32x4 v = *(const f32x4*)(ebf + rr * 132 + cc * 4);
        *(f32x4*)(Cf + (size_t)(brow + half * 64 + rr) * D_ + bcol + cc * 4) = v;
      }
    }
  } else {
    const int t = bcol >> 11;                     // block-uniform (256 | 2048)
    const int b = brow >> 11, sbase = brow & (S_ - 1);
    __syncthreads();                              // main-loop LDS dead across ALL waves
    bf16* eb = (bf16*)smem;
    if (t == 2) {
      // v: LDS tile [cc 256][rr 128] pitch 136 (272B rows: 16B-aligned, ~2-way write bank)
#pragma unroll
      for (int mf = 0; mf < 4; ++mf)
#pragma unroll
        for (int nf = 0; nf < NF; ++nf) {
          const int cc = wn * (NF * 16) + nf * 16 + lr;
          const int rr0 = wm * 64 + mf * 16 + lg * 4;
          u16x4 pk;
#pragma unroll
          for (int j = 0; j < 4; ++j) pk[j] = f2bf_u(acc[mf][nf][j]);
          *(u16x4*)(eb + cc * 136 + rr0) = pk;
        }
      __syncthreads();
      // readout: 256x128 els = 4096 16B-chunks, 8/thread, fully coalesced stores
#pragma unroll
      for (int i = 0; i < 8; ++i) {
        const int ch = i * 512 + tid;
        const int cc = ch >> 4, sc = (ch & 15) * 8;
        const bf16x8 v = *(const bf16x8*)(eb + cc * 136 + sc);
        const int h = ((bcol & (D_ - 1)) >> 7) + (cc >> 7);
        const int mm = cc & (HD_ - 1);
        *(bf16x8*)(vt + ((size_t)(b * H_ + h) * HD_ + mm) * S_ + sbase + sc) = v;
      }
    } else {
      // q/k with RoPE: LDS tile [rr 128][oc 256] pitch 264 (528B rows: 16B-aligned)
#pragma unroll
      for (int mf = 0; mf < 4; ++mf)
#pragma unroll
        for (int nf = 0; nf < NF; ++nf) {
          const int cc = wn * (NF * 16) + nf * 16 + lr;
          const int hh = cc >> 7, mm = cc & (HD_ - 1);
          const int i2 = mm >> 1;
          const bool odd = mm & 1;
          const int oc = hh * 128 + (odd ? (64 + i2) : i2);
#pragma unroll
          for (int j = 0; j < 4; ++j) {
            const int rr = wm * 64 + mf * 16 + lg * 4 + j;
            const int s = sbase + rr;
            const float val = acc[mf][nf][j];
            const float part = __shfl_xor(val, 1, 64);   // col parity == lane parity
            const float c = cost[s * 64 + i2];
            const float sn = sint[s * 64 + i2];
            float o = odd ? (part * sn + val * c) : (val * c - part * sn);
            if (t == 0) o *= SCALE_;
            eb[rr * 264 + oc] = __float2bfloat16(o);
          }
        }
      __syncthreads();
      bf16* dst = (t == 1) ? kb : qb;
      // readout: 128x256 els = 4096 16B-chunks, 8/thread, fully coalesced stores
#pragma unroll
      for (int i = 0; i < 8; ++i) {
        const int ch = i * 512 + tid;
        const int rr = ch >> 5, oc0 = (ch & 31) * 8;
        const bf16x8 v = *(const bf16x8*)(eb + rr * 264 + oc0);
        const int h = ((bcol & (D_ - 1)) >> 7) + (oc0 >> 7);
        const int om0 = oc0 & (HD_ - 1);
        *(bf16x8*)(dst + ((size_t)(b * H_ + h) * S_ + sbase + rr) * HD_ + om0) = v;
      }
    }
  }
}

// ---------------- flash attention: 512 threads, 8 waves x ONE 16-row group (round-18 exact) ----------------
__global__ __launch_bounds__(512, 4) void k_attn(const bf16* __restrict__ qb,
                                                 const bf16* __restrict__ kb,
                                                 const bf16* __restrict__ vt,
                                                 const int* __restrict__ mask,
                                                 bf16* __restrict__ attn_b) {
  const int tid = threadIdx.x, w = tid >> 6, lane = tid & 63;
  const int lr = lane & 15, lg = lane >> 4;
  const int qt = (blockIdx.y < 16) ? ((int)gridDim.x - 1 - (int)blockIdx.x)
                                   : (int)blockIdx.x;   // complementary CU pairing
  const int q0 = qt * 128;
  const int bh = blockIdx.y;
  const int b = bh >> 4, h = bh & (H_ - 1);
  const bf16* qp = qb + (size_t)bh * S_ * HD_;
  const bf16* kp = kb + (size_t)bh * S_ * HD_;
  const bf16* vp = vt + (size_t)bh * HD_ * S_;
  __shared__ __align__(16) bf16 Ks[2][64 * 128];   // 2 x 16 KB, XOR-swizzled rows
  __shared__ __align__(16) bf16 Vs[2][128 * 64];   // 2 x 16 KB, XOR-swizzled rows
  __shared__ __align__(16) bf16 Ps[8][16][40];     // per-wave half-P scratch

  const int qrow = q0 + w * 16 + lr;
  bf16x8 qf[4];
#pragma unroll
  for (int ks = 0; ks < 4; ++ks)
    qf[ks] = *(const bf16x8*)(qp + (size_t)qrow * HD_ + ks * 32 + lg * 8);

  float m_run[4], l_run[4];
  f32x4 oacc[8];
#pragma unroll
  for (int j = 0; j < 4; ++j) { m_run[j] = -INFINITY; l_run[j] = 0.f; }
#pragma unroll
  for (int c = 0; c < 8; ++c) oacc[c] = (f32x4)(0.f);

  auto stage = [&](int buf, int k0) {
#pragma unroll
    for (int i = 0; i < 2; ++i) {
      const int slot = i * 512 + tid;
      const int row = slot >> 4, j16 = slot & 15;
      load_lds16(kp + (size_t)(k0 + row) * HD_ + ((j16 ^ (row & 7)) * 8),
                 (char*)&Ks[buf][0] + i * 8192 + w * 1024);
    }
#pragma unroll
    for (int i = 0; i < 2; ++i) {
      const int slot = i * 512 + tid;
      const int row = slot >> 3, j8 = slot & 7;
      load_lds16(vp + (size_t)row * S_ + k0 + ((j8 ^ (row & 7)) * 8),
                 (char*)&Vs[buf][0] + i * 8192 + w * 1024);
    }
  };

  const int nt = 2 * qt + 2;
  stage(0, 0);
  asm volatile("s_waitcnt vmcnt(0)" ::: "memory");
  __builtin_amdgcn_s_barrier();
  __builtin_amdgcn_sched_barrier(0);

  int cur = 0;
  for (int it = 0; it < nt; ++it) {
    const int k0 = it * 64;
    if (it + 1 < nt) stage(cur ^ 1, k0 + 64);   // prefetch next tile (in flight across compute)

    // waves 0-3: rows q0+w*16..+15 all < q0+64 <= k0 on the last tile -> fully masked, skip
    const bool active = (it + 1 < nt) || (w >= 4);

    if (active) {
      int mk4[4];
#pragma unroll
      for (int n = 0; n < 4; ++n) mk4[n] = mask[b * S_ + k0 + n * 16 + lr];

      const bf16* ksb = &Ks[cur][0];
      const bf16* vsb = &Vs[cur][0];

      // QK^T: 16 q-rows x 64 k
      f32x4 sacc[4] = {};
      __builtin_amdgcn_s_setprio(1);
#pragma unroll
      for (int n = 0; n < 4; ++n) {
        const int krow = n * 16 + lr;
#pragma unroll
        for (int ks = 0; ks < 4; ++ks) {
          const int j16 = (ks * 4 + lg) ^ (krow & 7);
          const bf16x8 kf = *(const bf16x8*)(ksb + krow * 128 + j16 * 8);
          sacc[n] = __builtin_amdgcn_mfma_f32_16x16x32_bf16(qf[ks], kf, sacc[n], 0, 0, 0);
        }
      }
      __builtin_amdgcn_s_setprio(0);

      // mask + row max
      float mblk[4] = {-INFINITY, -INFINITY, -INFINITY, -INFINITY};
#pragma unroll
      for (int n = 0; n < 4; ++n) {
        const int kcol = k0 + n * 16 + lr;
#pragma unroll
        for (int j = 0; j < 4; ++j) {
          const int r = q0 + w * 16 + lg * 4 + j;
          float sv = sacc[n][j];
          const bool allowed = (kcol <= r) && (mk4[n] != 0 || kcol == r);
          sv = allowed ? sv : -1e9f;
          sacc[n][j] = sv;
          mblk[j] = fmaxf(mblk[j], sv);
        }
      }
#pragma unroll
      for (int xm = 1; xm < 16; xm <<= 1)
#pragma unroll
        for (int j = 0; j < 4; ++j)
          mblk[j] = fmaxf(mblk[j], __shfl_xor(mblk[j], xm, 64));

      // defer-max (T13); l_run is a per-lane partial, rescale is row-uniform
      bool grow = false;
#pragma unroll
      for (int j = 0; j < 4; ++j) grow = grow || (mblk[j] > m_run[j] + 8.f);
      if (__any(grow)) {
        float alpha[4];
#pragma unroll
        for (int j = 0; j < 4; ++j) {
          const float mn = fmaxf(m_run[j], mblk[j]);
          alpha[j] = __expf(m_run[j] - mn);
          m_run[j] = mn;
          l_run[j] *= alpha[j];
        }
#pragma unroll
        for (int c = 0; c < 8; ++c)
#pragma unroll
          for (int j = 0; j < 4; ++j) oacc[c][j] *= alpha[j];
      }

      // p = exp(s - m); accumulate per-lane l partials (NO per-iter cross-lane reduce)
#pragma unroll
      for (int n = 0; n < 4; ++n)
#pragma unroll
        for (int j = 0; j < 4; ++j) {
          const float p = __expf(sacc[n][j] - m_run[j]);
          l_run[j] += p;
          sacc[n][j] = p;
        }

      // PV in two 32-col halves through the per-wave half-P scratch (in-order reuse)
#pragma unroll
      for (int hh = 0; hh < 2; ++hh) {
#pragma unroll
        for (int n2 = 0; n2 < 2; ++n2)
#pragma unroll
          for (int j = 0; j < 4; ++j)
            Ps[w][lg * 4 + j][n2 * 16 + lr] = __float2bfloat16(sacc[hh * 2 + n2][j]);
        const bf16x8 pa = *(const bf16x8*)(&Ps[w][lr][lg * 8]);
        __builtin_amdgcn_s_setprio(1);
#pragma unroll
        for (int c = 0; c < 8; ++c) {
          const int vrow = c * 16 + lr;
          const int unit = (hh * 4 + lg) ^ (vrow & 7);
          const bf16x8 vf = *(const bf16x8*)(vsb + vrow * 64 + unit * 8);
          oacc[c] = __builtin_amdgcn_mfma_f32_16x16x32_bf16(pa, vf, oacc[c], 0, 0, 0);
        }
        __builtin_amdgcn_s_setprio(0);
      }
    }

    asm volatile("s_waitcnt vmcnt(0)" ::: "memory");  // next tile staged (all waves)
    __builtin_amdgcn_s_barrier();                      // raw: no redundant re-drain
    __builtin_amdgcn_sched_barrier(0);
    cur ^= 1;
  }

  // epilogue: single cross-lane l reduce, then normalize and write attn_b [B,S,H*hd] bf16
#pragma unroll
  for (int xm = 1; xm < 16; xm <<= 1)
#pragma unroll
    for (int j = 0; j < 4; ++j)
      l_run[j] += __shfl_xor(l_run[j], xm, 64);
#pragma unroll
  for (int j = 0; j < 4; ++j) {
    const float inv = 1.f / l_run[j];
    const int r = q0 + w * 16 + lg * 4 + j;
#pragma unroll
    for (int c = 0; c < 8; ++c)
      attn_b[(size_t)(b * S_ + r) * D_ + h * HD_ + c * 16 + lr] =
          __float2bfloat16(oacc[c][j] * inv);
  }
}

extern "C" void kernel_launch(void* const* d_in, const int* in_sizes, int n_in,
                              void* d_out, int out_size, void* d_ws, size_t ws_size,
                              hipStream_t stream) {
  (void)in_sizes; (void)n_in; (void)out_size; (void)ws_size;
  const float* x        = (const float*)d_in[0];
  const int*   attn_mask= (const int*)d_in[1];
  const float* in_proj  = (const float*)d_in[2];
  const float* out_proj = (const float*)d_in[3];
  float* out = (float*)d_out;
  char* ws = (char*)d_ws;

  bf16*  xb    = (bf16*)(ws + 0);            // 16 MB (also attn_b later)
  bf16*  wqkvT = (bf16*)(ws + 16777216);     // 24 MB  ([3][2048][2048] = [6144][2048])
  bf16*  woT   = (bf16*)(ws + 41943040);     //  8 MB
  float* cost  = (float*)(ws + 50331648);
  float* sint  = (float*)(ws + 50855936);
  bf16*  vt    = (bf16*)(ws + 51380224);     // 16 MB
  bf16* qb = (bf16*)d_out;                   // d_out as scratch (dead before final GEMM)
  bf16* kb = (bf16*)((char*)d_out + 16777216);
  bf16* attn_b = xb;

  // allow dynamic LDS (host-side, graph-capture safe)
  static int lds_ok = 0;
  if (!lds_ok) {
    (void)hipFuncSetAttribute((const void*)k_gemm_p<0>,
                              hipFuncAttributeMaxDynamicSharedMemorySize, 73728);
    (void)hipFuncSetAttribute((const void*)k_gemm_p<1>,
                              hipFuncAttributeMaxDynamicSharedMemorySize, 33792);
    lds_ok = 1;
  }

  k_prep<<<8704, 256, 0, stream>>>(x, xb, in_proj, wqkvT, out_proj, woT, cost, sint);
  k_gemm_p<0><<<dim3(32, 24), 512, 73728, stream>>>(xb, wqkvT, nullptr, qb, kb, vt, cost, sint);
  k_attn<<<dim3(16, 32), 512, 0, stream>>>(qb, kb, vt, attn_mask, attn_b);
  k_gemm_p<1><<<dim3(32, 16), 512, 33792, stream>>>(attn_b, woT, out, nullptr, nullptr, nullptr,
                                                    nullptr, nullptr);
}